// Round 1
// baseline (133.651 us; speedup 1.0000x reference)
//
#include <hip/hip_runtime.h>

#define NH    8
#define BROWS 32768
#define INF   16
#define CIN   32
#define OUTF  32
#define KTOT  544   // OUTF*(INF+1)

typedef __attribute__((ext_vector_type(8))) short short8;
typedef __attribute__((ext_vector_type(4))) float floatx4;

__device__ __forceinline__ short f2bf(float f) {
    __bf16 h = (__bf16)f;   // RNE f32->bf16
    return __builtin_bit_cast(short, h);
}

// Grid: (128, 8). Block: 256 threads = 4 waves.
// Wave w: pair = w>>1 (row-tile group), otile = w&1 (output half 0..15 / 16..31).
// Each pair of waves processes 8 contiguous 16-row tiles of one head.
// Per wave: B-fragments of W (17 x short8) live in registers for the whole block.
__global__ __launch_bounds__(256) void meta_multilinear(
    const float* __restrict__ input,
    const float* __restrict__ cond,
    const float* __restrict__ weight,
    const float* __restrict__ bias,
    float* __restrict__ out)
{
    const int tid   = threadIdx.x;
    const int lane  = tid & 63;
    const int wave  = tid >> 6;     // 0..3
    const int pair  = wave >> 1;    // 0..1
    const int otile = wave & 1;     // 0..1
    const int r     = lane & 15;    // A-row / D-col index
    const int quad  = lane >> 4;    // 0..3
    const int c0    = quad * 8;     // k-slice start

    const int h = blockIdx.y;
    const int o = otile * 16 + r;   // this lane's B column (output feature)

    const float* Wh = weight + (size_t)h * KTOT * CIN;
    const float* bh = bias   + (size_t)h * KTOT;

    // ---- register-resident B fragments: B[k=c][n=o] = W[h][o*17+i][c] ----
    short8 bfrag[17];
    #pragma unroll
    for (int i = 0; i < 17; ++i) {
        const float* src = Wh + (o * 17 + i) * CIN + c0;
        floatx4 w0 = *(const floatx4*)(src);
        floatx4 w1 = *(const floatx4*)(src + 4);
        short8 f;
        f[0]=f2bf(w0.x); f[1]=f2bf(w0.y); f[2]=f2bf(w0.z); f[3]=f2bf(w0.w);
        f[4]=f2bf(w1.x); f[5]=f2bf(w1.y); f[6]=f2bf(w1.z); f[7]=f2bf(w1.w);
        bfrag[i] = f;
    }

    // ---- bias B' fragment: B'[k=i][n=o] = bias[h][o*17+i], zero for i>=17 ----
    short8 bbias;
    #pragma unroll
    for (int j = 0; j < 8; ++j) {
        const int i = c0 + j;
        short v = 0;
        if (i < 17) v = f2bf(bh[o * 17 + i]);   // exec-masked: no OOB load
        bbias[j] = v;
    }

    const int pairId = blockIdx.x * 2 + pair;   // 0..255 per head

    for (int it = 0; it < 8; ++it) {
        const int b0 = (pairId * 8 + it) * 16;

        // lane's cond slice: cond[h][b0+r][c0..c0+8)  (full wave = contiguous 2KB)
        const float* crow = cond + ((size_t)h * BROWS + b0 + r) * CIN + c0;
        floatx4 cA = *(const floatx4*)(crow);
        floatx4 cB = *(const floatx4*)(crow + 4);

        // lane's x1 row: input[h][b0+r][0..16), plus homogeneous 1
        const float* xrow = input + ((size_t)h * BROWS + b0 + r) * INF;
        floatx4 x0 = *(const floatx4*)(xrow);
        floatx4 x1v = *(const floatx4*)(xrow + 4);
        floatx4 x2 = *(const floatx4*)(xrow + 8);
        floatx4 x3 = *(const floatx4*)(xrow + 12);
        const float xr[17] = {x0.x,x0.y,x0.z,x0.w, x1v.x,x1v.y,x1v.z,x1v.w,
                              x2.x,x2.y,x2.z,x2.w, x3.x,x3.y,x3.z,x3.w, 1.0f};

        floatx4 acc = {0.f, 0.f, 0.f, 0.f};

        // ---- bias MFMA: A'[m=r][k=i] = x1[b0+r][i] (zero-padded K) ----
        {
            short8 af;
            if (quad == 0) {
                af[0]=f2bf(xr[0]); af[1]=f2bf(xr[1]); af[2]=f2bf(xr[2]); af[3]=f2bf(xr[3]);
                af[4]=f2bf(xr[4]); af[5]=f2bf(xr[5]); af[6]=f2bf(xr[6]); af[7]=f2bf(xr[7]);
            } else if (quad == 1) {
                af[0]=f2bf(xr[8]);  af[1]=f2bf(xr[9]);  af[2]=f2bf(xr[10]); af[3]=f2bf(xr[11]);
                af[4]=f2bf(xr[12]); af[5]=f2bf(xr[13]); af[6]=f2bf(xr[14]); af[7]=f2bf(xr[15]);
            } else if (quad == 2) {
                af[0]=f2bf(1.0f); af[1]=0; af[2]=0; af[3]=0;
                af[4]=0; af[5]=0; af[6]=0; af[7]=0;
            } else {
                af[0]=0; af[1]=0; af[2]=0; af[3]=0;
                af[4]=0; af[5]=0; af[6]=0; af[7]=0;
            }
            acc = __builtin_amdgcn_mfma_f32_16x16x32_bf16(af, bbias, acc, 0, 0, 0);
        }

        // ---- main loop: A_i[m=r][k=c] = cond[b0+r][c] * x1[b0+r][i] ----
        #pragma unroll
        for (int i = 0; i < 17; ++i) {
            const float s = xr[i];
            short8 af;
            af[0]=f2bf(cA.x*s); af[1]=f2bf(cA.y*s); af[2]=f2bf(cA.z*s); af[3]=f2bf(cA.w*s);
            af[4]=f2bf(cB.x*s); af[5]=f2bf(cB.y*s); af[6]=f2bf(cB.z*s); af[7]=f2bf(cB.w*s);
            acc = __builtin_amdgcn_mfma_f32_16x16x32_bf16(af, bfrag[i], acc, 0, 0, 0);
        }

        // ---- store: D row=(quad*4+j), col=o ----
        float* orow = out + ((size_t)h * BROWS + b0) * OUTF;
        #pragma unroll
        for (int j = 0; j < 4; ++j) {
            orow[(quad * 4 + j) * OUTF + o] = acc[j];
        }
    }
}

extern "C" void kernel_launch(void* const* d_in, const int* in_sizes, int n_in,
                              void* d_out, int out_size, void* d_ws, size_t ws_size,
                              hipStream_t stream) {
    const float* input  = (const float*)d_in[0];
    const float* cond   = (const float*)d_in[1];
    const float* weight = (const float*)d_in[2];
    const float* bias   = (const float*)d_in[3];
    float* out = (float*)d_out;

    dim3 grid(128, NH, 1);
    dim3 block(256, 1, 1);
    hipLaunchKernelGGL(meta_multilinear, grid, block, 0, stream,
                       input, cond, weight, bias, out);
}